// Round 1
// 108.210 us; speedup vs baseline: 1.1173x; 1.1173x over previous
//
#include <hip/hip_runtime.h>

#define ALG_DIM 248
#define ROWS 32                    // rows per main-kernel block
#define KSPLIT 4
#define KPB 62                     // k-slots per block (248/4)
#define CAP 256                    // uint2 capacity per bucket (pow2; max bucket ~160)
#define CNT_STRIDE 16              // ints between cursors (64 B -> spread L2 lines)
#define PLSTRIDE_B 3984            // plane stride bytes (248*16 + 16; /4 = 996 ≡ 4 mod 32)
#define PLSTRIDE_DW 996

typedef __fp16 h2v __attribute__((ext_vector_type(2)));
union H2U { unsigned u; h2v h; };

// ---------- prep: ONE single-pass scatter (global-atomic cursors) ----------
// The cursor+packed region (512 KB) is zeroed by a hipMemsetAsync node before
// this kernel. Zero packed entries are exact no-ops in k_main (c=0, offs=0),
// so bucket tails need no explicit padding pass. Final cursor value == bucket
// size, which k_main reads directly. Order within a bucket is nondeterministic
// (atomics) -> only FP-rounding-level output differences.

__global__ void k_scatter(const int* __restrict__ idx_i, const int* __restrict__ idx_j,
                          const int* __restrict__ idx_k, const float* __restrict__ coeff,
                          int* __restrict__ cnt, uint2* __restrict__ packed, int nnz) {
    const int t = blockIdx.x * 256 + threadIdx.x;
    if (t >= nnz) return;
    const int k = idx_k[t];
    const int pos = atomicAdd(&cnt[k * CNT_STRIDE], 1);
    if (pos < CAP - 8) {                       // safety clamp (structurally unreachable)
        const float c = coeff[t];
        H2U hc; hc.h = __builtin_amdgcn_cvt_pkrtz(c, c);
        uint2 p;
        p.x = ((unsigned)idx_i[t] << 4) | ((unsigned)idx_j[t] << 20);
        p.y = hc.u;
        packed[((size_t)k << 8) + pos] = p;
    }
}

// ---------- main: plane-layout f16 gather, packed FMA, windowed fp32 flush ----
// 256 threads = 64 streams x 4 lanes over 32 rows x 62 slots. x,y in LDS as
// f16 in 4 planes: (col i, rows 8s..8s+7) at byte s*3984 + i*16. Lane q folds
// q*3984 into its base pointer once; gather = ds_read_b128 at base + i*16,
// bank window (i*4 + 4q) mod 32 sweeps all 32 banks as i varies.
// Body: 12 VALU/triple + 2 b128. f16 accs flushed to fp32 every 32 triples.
// Slots are unsorted now: each wave computes trip = round8(max size of its
// 16 streams) via 4x shfl_xor (sizes read from the scatter cursors).

__global__ __launch_bounds__(256, 4) void k_main(
    const float* __restrict__ x, const float* __restrict__ y,
    const uint4* __restrict__ packed4,
    const int* __restrict__ cnt,
    const float* __restrict__ alpha_p, float* __restrict__ out)
{
    __shared__ __align__(16) unsigned xs32[4 * PLSTRIDE_DW];
    __shared__ __align__(16) unsigned ys32[4 * PLSTRIDE_DW];

    const int tid = threadIdx.x;
    const int r0  = blockIdx.x * ROWS;

    for (int u = tid; u < (ALG_DIM / 4) * (ROWS / 2); u += 256) {
        const int rp = u & 15;
        const int cq = u >> 4;
        const size_t ra = (size_t)(r0 + 2 * rp) * ALG_DIM + 4 * cq;
        const float4 xa = *reinterpret_cast<const float4*>(x + ra);
        const float4 xb = *reinterpret_cast<const float4*>(x + ra + ALG_DIM);
        const float4 ya = *reinterpret_cast<const float4*>(y + ra);
        const float4 yb = *reinterpret_cast<const float4*>(y + ra + ALG_DIM);
        const int pbase = (rp >> 2) * PLSTRIDE_DW + (rp & 3);
#define STG(d, XA, XB, YA, YB)                                                  \
        {                                                                       \
            const int dw = pbase + (4 * cq + (d)) * 4;                          \
            H2U hx; hx.h = __builtin_amdgcn_cvt_pkrtz(XA, XB);                  \
            H2U hy; hy.h = __builtin_amdgcn_cvt_pkrtz(YA, YB);                  \
            xs32[dw] = hx.u;                                                    \
            ys32[dw] = hy.u;                                                    \
        }
        STG(0, xa.x, xb.x, ya.x, yb.x)
        STG(1, xa.y, xb.y, ya.y, yb.y)
        STG(2, xa.z, xb.z, ya.z, yb.z)
        STG(3, xa.w, xb.w, ya.w, yb.w)
#undef STG
    }
    __syncthreads();

    const float alpha = alpha_p[0];
    const int   S     = tid >> 2;            // stream 0..63 (owns one slot)
    const int   q     = tid & 3;             // my plane (rows 8q..8q+7)

    const char* xsb = reinterpret_cast<const char*>(xs32) + q * PLSTRIDE_B;
    const char* ysb = reinterpret_cast<const char*>(ys32) + q * PLSTRIDE_B;

    // per-stream bucket size; wave-max over the 16 streams of this wave.
    // Computed by ALL lanes (streams >= KPB contribute 0) so the shuffles
    // run fully converged.
    const int p   = blockIdx.y * KPB + S;
    int msz = (S < KPB) ? cnt[p * CNT_STRIDE] : 0;
    int m = msz;
    m = max(m, __shfl_xor(m, 4));
    m = max(m, __shfl_xor(m, 8));
    m = max(m, __shfl_xor(m, 16));
    m = max(m, __shfl_xor(m, 32));
    const int trip = __builtin_amdgcn_readfirstlane((m + 7) & ~7);
    const int nH   = trip >> 1;              // uint4s (2 triples each)

    if (S < KPB) {
        const int k = p;                     // identity perm
        const uint4* tp = packed4 + ((size_t)p << 7);   // 128 uint4 per bucket

        float a0 = 0.f, a1 = 0.f, a2 = 0.f, a3 = 0.f,
              a4 = 0.f, a5 = 0.f, a6 = 0.f, a7 = 0.f;

        uint4 cur = tp[0];

#define PROC(PW, PC)                                                            \
        {                                                                       \
            const unsigned ox = (PW) & 0xFFFFu;                                 \
            const unsigned oy = (PW) >> 16;                                     \
            const uint4 wx = *reinterpret_cast<const uint4*>(xsb + ox);         \
            const uint4 wy = *reinterpret_cast<const uint4*>(ysb + oy);         \
            H2U cc; cc.u = (PC);                                                \
            H2U ux, uy;                                                         \
            ux.u = wx.x; uy.u = wy.x; c0 = (ux.h * uy.h) * cc.h + c0;           \
            ux.u = wx.y; uy.u = wy.y; c1 = (ux.h * uy.h) * cc.h + c1;           \
            ux.u = wx.z; uy.u = wy.z; c2 = (ux.h * uy.h) * cc.h + c2;           \
            ux.u = wx.w; uy.u = wy.w; c3 = (ux.h * uy.h) * cc.h + c3;           \
        }

        for (int chunk = 0; chunk < nH; chunk += 16) {       // 32-triple window
            h2v c0 = (h2v)0.0f, c1 = (h2v)0.0f, c2 = (h2v)0.0f, c3 = (h2v)0.0f;
            const int hend = min(chunk + 16, nH);
#pragma unroll 2
            for (int h = chunk; h < hend; ++h) {
                const uint4 nxt = tp[h + 1];  // prefetch (zeroed tail covers over-read)
                PROC(cur.x, cur.y)
                PROC(cur.z, cur.w)
                cur = nxt;
            }
            a0 += (float)c0.x; a1 += (float)c0.y;
            a2 += (float)c1.x; a3 += (float)c1.y;
            a4 += (float)c2.x; a5 += (float)c2.y;
            a6 += (float)c3.x; a7 += (float)c3.y;
        }
#undef PROC

        const int rbase = r0 + (q << 3);
        out[(size_t)(rbase + 0) * ALG_DIM + k] = alpha * a0;
        out[(size_t)(rbase + 1) * ALG_DIM + k] = alpha * a1;
        out[(size_t)(rbase + 2) * ALG_DIM + k] = alpha * a2;
        out[(size_t)(rbase + 3) * ALG_DIM + k] = alpha * a3;
        out[(size_t)(rbase + 4) * ALG_DIM + k] = alpha * a4;
        out[(size_t)(rbase + 5) * ALG_DIM + k] = alpha * a5;
        out[(size_t)(rbase + 6) * ALG_DIM + k] = alpha * a6;
        out[(size_t)(rbase + 7) * ALG_DIM + k] = alpha * a7;
    }
}

// ---------- launch ----------

extern "C" void kernel_launch(void* const* d_in, const int* in_sizes, int n_in,
                              void* d_out, int out_size, void* d_ws, size_t ws_size,
                              hipStream_t stream) {
    const float* x      = (const float*)d_in[0];
    const float* y      = (const float*)d_in[1];
    const int*   idx_i  = (const int*)d_in[2];
    const int*   idx_j  = (const int*)d_in[3];
    const int*   idx_k  = (const int*)d_in[4];
    const float* coeff  = (const float*)d_in[5];
    const float* alpha  = (const float*)d_in[6];
    float*       out    = (float*)d_out;

    const int nnz   = in_sizes[2];
    const int batch = in_sizes[0] / ALG_DIM;

    // ws: [cnt @0, 248*64B = 15872 (rounded to 16K)][packed @16384, 248*256*8 = 507904]
    char*  ws     = (char*)d_ws;
    int*   cnt    = (int*)ws;
    uint2* packed = (uint2*)(ws + 16384);

    const size_t zbytes = 16384 + (size_t)ALG_DIM * CAP * sizeof(uint2);
    hipMemsetAsync(ws, 0, zbytes, stream);

    k_scatter<<<(nnz + 255) / 256, 256, 0, stream>>>(idx_i, idx_j, idx_k, coeff,
                                                     cnt, packed, nnz);

    dim3 grid(batch / ROWS, KSPLIT);
    k_main<<<grid, 256, 0, stream>>>(x, y, (const uint4*)packed, cnt, alpha, out);
}